// Round 2
// baseline (1343.856 us; speedup 1.0000x reference)
//
#include <hip/hip_runtime.h>
#include <stdint.h>

#define TT 7
#define CC 256
#define NPOSC 36864   // B*H*W = 4*96*96

typedef unsigned int uint;
typedef unsigned short ushort_t;
typedef __attribute__((ext_vector_type(8))) short short8;
typedef __attribute__((ext_vector_type(4))) float f32x4;

__device__ inline float bf2f(ushort_t u) {
    union { uint i; float f; } v; v.i = ((uint)u) << 16; return v.f;
}
__device__ inline ushort_t f2bf(float f) {
    union { float f; uint i; } v; v.f = f;
    uint i = v.i;
    return (ushort_t)((i + 0x7FFFu + ((i >> 16) & 1u)) >> 16);
}
__device__ inline uint pack2(float a, float b) {
    return (uint)f2bf(a) | (((uint)f2bf(b)) << 16);
}
__device__ inline short8 as_s8(uint4 v) {
    union { uint4 u; short8 s; } x; x.u = v; return x.s;
}

// ---------------------------------------------------------------------------
// prep: blocks 0..63  -> 64x64-tile transposes (fp32 -> bf16) of Wq,Wk,Wv
//                        -> WTall[768][256]; Wo -> WoT[c][nd]
//       blocks 64..84 -> biasC[t][768] = {bq, bk, bv - emb[t]*Wv}   (fp32)
// ---------------------------------------------------------------------------
__global__ void prep_kernel(const float* __restrict__ Wq, const float* __restrict__ Wk,
                            const float* __restrict__ Wv, const float* __restrict__ Wo,
                            const float* __restrict__ bq, const float* __restrict__ bk,
                            const float* __restrict__ bv, const float* __restrict__ temb,
                            ushort_t* __restrict__ WTall, ushort_t* __restrict__ WoT,
                            float* __restrict__ biasC)
{
    int bx = blockIdx.x, tid = threadIdx.x;
    if (bx < 64) {
        __shared__ __align__(16) ushort_t tl[64][72];   // 72*2=144B row stride (16B-mult)
        int m = bx >> 4, tile = bx & 15;
        int tr = (tile >> 2) * 64, tc = (tile & 3) * 64;
        const float* src = (m == 0) ? Wq : (m == 1) ? Wk : (m == 2) ? Wv : Wo;
        ushort_t* dst = (m < 3) ? (WTall + m * 65536) : WoT;
        int lr = tid >> 2, lc = (tid & 3) * 16;
        const float* sp = src + (size_t)(tr + lr) * 256 + tc + lc;
        #pragma unroll
        for (int q = 0; q < 4; ++q) {
            float4 x = *(const float4*)(sp + q * 4);
            tl[lr][lc + q * 4 + 0] = f2bf(x.x);
            tl[lr][lc + q * 4 + 1] = f2bf(x.y);
            tl[lr][lc + q * 4 + 2] = f2bf(x.z);
            tl[lr][lc + q * 4 + 3] = f2bf(x.w);
        }
        __syncthreads();
        uint w[8];
        #pragma unroll
        for (int j = 0; j < 8; ++j) {
            ushort_t e0 = tl[lc + 2 * j][lr];
            ushort_t e1 = tl[lc + 2 * j + 1][lr];
            w[j] = (uint)e0 | ((uint)e1 << 16);
        }
        uint4 o0, o1;
        o0.x = w[0]; o0.y = w[1]; o0.z = w[2]; o0.w = w[3];
        o1.x = w[4]; o1.y = w[5]; o1.z = w[6]; o1.w = w[7];
        *(uint4*)(dst + (size_t)(tc + lr) * 256 + tr + lc) = o0;
        *(uint4*)(dst + (size_t)(tc + lr) * 256 + tr + lc + 8) = o1;
    } else {
        int gid = (bx - 64) * 256 + tid;   // 0..5375
        int t = gid / 768, j = gid % 768;
        float val;
        if (j < 256) {
            val = bq[j];
        } else if (j < 512) {
            val = bk[j - 256];
        } else {
            int nd = j - 512;
            float acc = bv[nd];
            for (int c = 0; c < 256; ++c)
                acc -= temb[t * 256 + c] * Wv[(size_t)c * 256 + nd];
            val = acc;   // bv - emb*Wv  => V = (X+emb)*Wv + biasC
        }
        biasC[t * 768 + j] = val;
    }
}

// ---------------------------------------------------------------------------
// K1: qkvT[nd=768][t][pos] = WTall[nd][c] x bf16(frames[t][pos][c] + emb[t][c])
//                            + biasC     (fp32 in, bf16 out)
// block: (pos-tile 128, t). 4 waves = (mh,nh) 2x2. B(frames+emb) in registers,
// A (weight tiles, 64nd x 32c) double-buffered in LDS.
// ---------------------------------------------------------------------------
__launch_bounds__(256, 2)
__global__ void qkv_kernel(const float* __restrict__ frames, const float* __restrict__ temb,
                           const ushort_t* __restrict__ WTall, const float* __restrict__ biasC,
                           ushort_t* __restrict__ qkvT, int posBase, int Ps)
{
    int t = blockIdx.y;
    int pos0l = blockIdx.x * 128;
    int tid = threadIdx.x;
    int wave = tid >> 6, lane = tid & 63;
    int mh = wave >> 1, nh = wave & 1;
    int l15 = lane & 15, lg = lane >> 4;

    __shared__ __align__(16) ushort_t Atile[2][64][40];   // 40*2=80B stride (16B-mult)

    // --- load B fragments: KQ^T = frames + emb, 64 pos x 256 c per wave ---
    uint4 Breg[4][8];
    {
        const float* fb = frames + ((size_t)t * NPOSC + posBase + pos0l + nh * 64) * 256;
        #pragma unroll
        for (int kc = 0; kc < 8; ++kc) {
            float4 e0 = *(const float4*)(temb + t * 256 + kc * 32 + lg * 8);
            float4 e1 = *(const float4*)(temb + t * 256 + kc * 32 + lg * 8 + 4);
            #pragma unroll
            for (int nt = 0; nt < 4; ++nt) {
                const float* xp = fb + (size_t)(nt * 16 + l15) * 256 + kc * 32 + lg * 8;
                float4 x0 = *(const float4*)(xp);
                float4 x1 = *(const float4*)(xp + 4);
                uint4 r;
                r.x = pack2(x0.x + e0.x, x0.y + e0.y);
                r.y = pack2(x0.z + e0.z, x0.w + e0.w);
                r.z = pack2(x1.x + e1.x, x1.y + e1.y);
                r.w = pack2(x1.z + e1.z, x1.w + e1.w);
                Breg[nt][kc] = r;
            }
        }
    }

    f32x4 acc[2][4];
    const f32x4 z4 = {0.f, 0.f, 0.f, 0.f};
    #pragma unroll
    for (int mt = 0; mt < 2; ++mt)
        #pragma unroll
        for (int nt = 0; nt < 4; ++nt) acc[mt][nt] = z4;

    int srow = tid >> 2, sq4 = tid & 3;

    // prologue: stage (ndc=0,kc=0) into buffer 0
    {
        uint4 sv = *(const uint4*)(WTall + (size_t)srow * 256 + sq4 * 8);
        *(uint4*)&Atile[0][srow][sq4 * 8] = sv;
    }

    for (int ndc = 0; ndc < 12; ++ndc) {
        #pragma unroll
        for (int kc = 0; kc < 8; ++kc) {
            int it = ndc * 8 + kc;
            int buf = kc & 1;
            uint4 nxt;
            bool have = (it + 1 < 96);
            if (have) {
                int it1 = it + 1;
                nxt = *(const uint4*)(WTall + ((size_t)((it1 >> 3) * 64 + srow)) * 256
                                      + (it1 & 7) * 32 + sq4 * 8);
            }
            __syncthreads();
            if (have) *(uint4*)&Atile[buf ^ 1][srow][sq4 * 8] = nxt;

            uint4 af[2];
            #pragma unroll
            for (int mt = 0; mt < 2; ++mt)
                af[mt] = *(const uint4*)&Atile[buf][mh * 32 + mt * 16 + l15][lg * 8];
            #pragma unroll
            for (int mt = 0; mt < 2; ++mt)
                #pragma unroll
                for (int nt = 0; nt < 4; ++nt)
                    acc[mt][nt] = __builtin_amdgcn_mfma_f32_16x16x32_bf16(
                        as_s8(af[mt]), as_s8(Breg[nt][kc]), acc[mt][nt], 0, 0, 0);
        }
        // epilogue for this nd-chunk (64 rows)
        #pragma unroll
        for (int mt = 0; mt < 2; ++mt) {
            int ndbase = ndc * 64 + mh * 32 + mt * 16 + lg * 4;
            float bi[4];
            #pragma unroll
            for (int i = 0; i < 4; ++i) bi[i] = biasC[t * 768 + ndbase + i];
            #pragma unroll
            for (int nt = 0; nt < 4; ++nt) {
                int posl = pos0l + nh * 64 + nt * 16 + l15;
                #pragma unroll
                for (int i = 0; i < 4; ++i) {
                    float v = acc[mt][nt][i] + bi[i];
                    qkvT[((size_t)(ndbase + i) * 7 + t) * Ps + posl] = f2bf(v);
                }
                acc[mt][nt] = z4;
            }
        }
    }
}

// ---------------------------------------------------------------------------
// K2: attention per (pos, head). lane = position -> fully coalesced loads.
// qkvT rows: q = nd, k = 256+nd, v = 512+nd ; ctx written as [t*Ps+pos][256]
// ---------------------------------------------------------------------------
__global__ void attn_kernel(const ushort_t* __restrict__ qkvT, ushort_t* __restrict__ ctx, int Ps)
{
    int n = blockIdx.y;
    int pos = blockIdx.x * 256 + threadIdx.x;
    const float scale = 0.17677669529663687f;      // 1/sqrt(32)
    float s[7][7];
    #pragma unroll
    for (int a = 0; a < 7; ++a)
        #pragma unroll
        for (int b = 0; b < 7; ++b) s[a][b] = 0.f;

    const ushort_t* qp = qkvT + ((size_t)(n * 32) * 7) * Ps + pos;
    const ushort_t* kp = qkvT + ((size_t)(256 + n * 32) * 7) * Ps + pos;

    for (int d = 0; d < 32; ++d) {
        float qv[7], kv[7];
        #pragma unroll
        for (int i = 0; i < 7; ++i) qv[i] = bf2f(qp[(size_t)(d * 7 + i) * Ps]);
        #pragma unroll
        for (int i = 0; i < 7; ++i) kv[i] = bf2f(kp[(size_t)(d * 7 + i) * Ps]);
        #pragma unroll
        for (int a = 0; a < 7; ++a)
            #pragma unroll
            for (int b = 0; b < 7; ++b) s[a][b] += qv[a] * kv[b];
    }

    #pragma unroll
    for (int a = 0; a < 7; ++a) {
        float mx = -1e30f;
        #pragma unroll
        for (int b = 0; b < 7; ++b) { s[a][b] *= scale; mx = fmaxf(mx, s[a][b]); }
        float sum = 0.f;
        #pragma unroll
        for (int b = 0; b < 7; ++b) {
            float e = exp2f((s[a][b] - mx) * 1.4426950408889634f);
            s[a][b] = e; sum += e;
        }
        float r = 1.0f / sum;
        #pragma unroll
        for (int b = 0; b < 7; ++b) s[a][b] *= r;
    }

    const ushort_t* vp = qkvT + ((size_t)(512 + n * 32) * 7) * Ps + pos;
    #pragma unroll
    for (int dc = 0; dc < 4; ++dc) {
        float o[7][8];
        #pragma unroll
        for (int a = 0; a < 7; ++a)
            #pragma unroll
            for (int j = 0; j < 8; ++j) o[a][j] = 0.f;
        #pragma unroll
        for (int kt = 0; kt < 7; ++kt) {
            float vv[8];
            #pragma unroll
            for (int j = 0; j < 8; ++j)
                vv[j] = bf2f(vp[(size_t)((dc * 8 + j) * 7 + kt) * Ps]);
            #pragma unroll
            for (int a = 0; a < 7; ++a)
                #pragma unroll
                for (int j = 0; j < 8; ++j) o[a][j] += s[a][kt] * vv[j];
        }
        #pragma unroll
        for (int a = 0; a < 7; ++a) {
            uint4 wv;
            wv.x = pack2(o[a][0], o[a][1]);
            wv.y = pack2(o[a][2], o[a][3]);
            wv.z = pack2(o[a][4], o[a][5]);
            wv.w = pack2(o[a][6], o[a][7]);
            *(uint4*)(ctx + ((size_t)a * Ps + pos) * 256 + n * 32 + dc * 8) = wv;
        }
    }
}

// ---------------------------------------------------------------------------
// K3: out[t*NPOS+pos][c] = ctx[tp][nd] x Wo[nd][c] + bo[c]   (fp32 output)
// block: 128 rows x 128 cols, A = ctx (k-contig), B = WoT (k-contig), both LDS dbuf
// ---------------------------------------------------------------------------
__launch_bounds__(256, 2)
__global__ void out_kernel(const ushort_t* __restrict__ ctx, const ushort_t* __restrict__ WoT,
                           const float* __restrict__ bo, float* __restrict__ outp,
                           int posBase, int Ps)
{
    int rows0 = blockIdx.x * 128;
    int c0 = blockIdx.y * 128;
    int tid = threadIdx.x, wave = tid >> 6, lane = tid & 63;
    int mh = wave >> 1, nh = wave & 1;
    int l15 = lane & 15, lg = lane >> 4;

    __shared__ __align__(16) ushort_t At[2][128][40];
    __shared__ __align__(16) ushort_t Bt[2][128][40];

    f32x4 acc[4][4];
    const f32x4 z4 = {0.f, 0.f, 0.f, 0.f};
    #pragma unroll
    for (int mt = 0; mt < 4; ++mt)
        #pragma unroll
        for (int nt = 0; nt < 4; ++nt) acc[mt][nt] = z4;

    // stage kc=0
    #pragma unroll
    for (int p = 0; p < 2; ++p) {
        int ch = p * 256 + tid, row = ch >> 2, q4 = ch & 3;
        uint4 av = *(const uint4*)(ctx + (size_t)(rows0 + row) * 256 + q4 * 8);
        uint4 bv_ = *(const uint4*)(WoT + (size_t)(c0 + row) * 256 + q4 * 8);
        *(uint4*)&At[0][row][q4 * 8] = av;
        *(uint4*)&Bt[0][row][q4 * 8] = bv_;
    }

    #pragma unroll
    for (int kc = 0; kc < 8; ++kc) {
        int buf = kc & 1;
        uint4 na[2], nb[2];
        if (kc < 7) {
            #pragma unroll
            for (int p = 0; p < 2; ++p) {
                int ch = p * 256 + tid, row = ch >> 2, q4 = ch & 3;
                na[p] = *(const uint4*)(ctx + (size_t)(rows0 + row) * 256 + (kc + 1) * 32 + q4 * 8);
                nb[p] = *(const uint4*)(WoT + (size_t)(c0 + row) * 256 + (kc + 1) * 32 + q4 * 8);
            }
        }
        __syncthreads();
        if (kc < 7) {
            #pragma unroll
            for (int p = 0; p < 2; ++p) {
                int ch = p * 256 + tid, row = ch >> 2, q4 = ch & 3;
                *(uint4*)&At[buf ^ 1][row][q4 * 8] = na[p];
                *(uint4*)&Bt[buf ^ 1][row][q4 * 8] = nb[p];
            }
        }
        uint4 af[4], bfr[4];
        #pragma unroll
        for (int mt = 0; mt < 4; ++mt)
            af[mt] = *(const uint4*)&At[buf][mh * 64 + mt * 16 + l15][lg * 8];
        #pragma unroll
        for (int nt = 0; nt < 4; ++nt)
            bfr[nt] = *(const uint4*)&Bt[buf][nh * 64 + nt * 16 + l15][lg * 8];
        #pragma unroll
        for (int mt = 0; mt < 4; ++mt)
            #pragma unroll
            for (int nt = 0; nt < 4; ++nt)
                acc[mt][nt] = __builtin_amdgcn_mfma_f32_16x16x32_bf16(
                    as_s8(af[mt]), as_s8(bfr[nt]), acc[mt][nt], 0, 0, 0);
    }

    int t = rows0 / Ps;            // block entirely inside one t (Ps % 128 == 0)
    int prow = rows0 - t * Ps;
    size_t obase = (size_t)t * NPOSC + posBase + prow;
    #pragma unroll
    for (int nt = 0; nt < 4; ++nt) {
        int col = c0 + nh * 64 + nt * 16 + l15;
        float bov = bo[col];
        #pragma unroll
        for (int mt = 0; mt < 4; ++mt) {
            #pragma unroll
            for (int i = 0; i < 4; ++i) {
                int r = mh * 64 + mt * 16 + lg * 4 + i;
                outp[(obase + r) * 256 + col] = acc[mt][nt][i] + bov;
            }
        }
    }
}

// ---------------------------------------------------------------------------
extern "C" void kernel_launch(void* const* d_in, const int* in_sizes, int n_in,
                              void* d_out, int out_size, void* d_ws, size_t ws_size,
                              hipStream_t stream)
{
    const float* frames = (const float*)d_in[0];
    const float* temb   = (const float*)d_in[1];
    const float* Wq = (const float*)d_in[2];
    const float* bq = (const float*)d_in[3];
    const float* Wk = (const float*)d_in[4];
    const float* bk = (const float*)d_in[5];
    const float* Wv = (const float*)d_in[6];
    const float* bv = (const float*)d_in[7];
    const float* Wo = (const float*)d_in[8];
    const float* bo = (const float*)d_in[9];
    float* outp = (float*)d_out;

    char* w = (char*)d_ws;
    ushort_t* WTall = (ushort_t*)w;               // 768*256*2      = 393216
    ushort_t* WoT   = (ushort_t*)(w + 393216);    // 256*256*2      = 131072
    float*    biasC = (float*)(w + 524288);       // 7*768*4        = 21504
    const size_t fixed = 557056;

    // choose slab count so ws fits: qkvT = 768*7*Ps*2, ctx = 7*Ps*256*2
    int s = 1;
    for (; s < 16; s *= 2) {
        size_t Ps_ = (size_t)NPOSC / s;
        size_t need = fixed + 768ull * 7 * Ps_ * 2 + 7ull * Ps_ * 256 * 2;
        if (need <= ws_size) break;
    }
    int Ps = NPOSC / s;
    ushort_t* qkvT = (ushort_t*)(w + fixed);
    ushort_t* ctxp = (ushort_t*)(w + fixed + (size_t)768 * 7 * Ps * 2);

    prep_kernel<<<85, 256, 0, stream>>>(Wq, Wk, Wv, Wo, bq, bk, bv, temb,
                                        WTall, WoT, biasC);
    for (int sl = 0; sl < s; ++sl) {
        int posBase = sl * Ps;
        qkv_kernel<<<dim3(Ps / 128, 7), 256, 0, stream>>>(frames, temb, WTall, biasC,
                                                          qkvT, posBase, Ps);
        attn_kernel<<<dim3(Ps / 256, 8), 256, 0, stream>>>(qkvT, ctxp, Ps);
        out_kernel<<<dim3(7 * Ps / 128, 2), 256, 0, stream>>>(ctxp, WoT, bo, outp,
                                                              posBase, Ps);
    }
}